// Round 3
// baseline (1138.083 us; speedup 1.0000x reference)
//
#include <hip/hip_runtime.h>
#include <math.h>

// ---------------------------------------------------------------------------
// GCN via CSR-gather (no feature atomics), workspace capped at 97N floats
// (38.8 MB — R0-proven safe bound):
//   perm[E] | h1[32N] | h[32N] (cnt+bsum alias here pre-gather) | deg[N] | rowptr[N]
//   h2[16N] aliases h1 (h1 dead after gather32).
// Gathers read src/ew through perm from the read-only inputs.
// Outputs (concat): r[N], x1f[N]
// ---------------------------------------------------------------------------

#define TPB 256

__device__ __forceinline__ float atomAddF(float* p, float v) {
    return unsafeAtomicAdd(p, v);   // native global_atomic_add_f32 on gfx950
}

// cnt[dst]++ ; deg[dst] += w
__global__ __launch_bounds__(TPB) void hist_kernel(const int* __restrict__ dst,
                                                   const float* __restrict__ ew,
                                                   int* __restrict__ cnt,
                                                   float* __restrict__ deg, int E) {
    int e = blockIdx.x * TPB + threadIdx.x;
    if (e < E) {
        int d = dst[e];
        atomicAdd(&cnt[d], 1);
        atomAddF(&deg[d], ew[e]);
    }
}

// deg -> dinv = 1/sqrt(deg+1)  (in place)
__global__ __launch_bounds__(TPB) void dinv_kernel(float* __restrict__ deg, int N) {
    int i = blockIdx.x * TPB + threadIdx.x;
    if (i < N) deg[i] = 1.0f / sqrtf(deg[i] + 1.0f);
}

// ---- 3-kernel exclusive scan over cnt[N] -> rowptr[N] ---------------------
__global__ __launch_bounds__(TPB) void scan1_kernel(const int* __restrict__ cnt,
                                                    int* __restrict__ rowptr,
                                                    int* __restrict__ bsum, int N) {
    __shared__ int s[TPB];
    int t = threadIdx.x;
    int base = blockIdx.x * 1024 + t * 4;
    int v0 = 0, v1 = 0, v2 = 0, v3 = 0;
    if (base + 0 < N) v0 = cnt[base + 0];
    if (base + 1 < N) v1 = cnt[base + 1];
    if (base + 2 < N) v2 = cnt[base + 2];
    if (base + 3 < N) v3 = cnt[base + 3];
    int tsum = v0 + v1 + v2 + v3;
    s[t] = tsum;
    __syncthreads();
    for (int off = 1; off < TPB; off <<= 1) {
        int x = (t >= off) ? s[t - off] : 0;
        __syncthreads();
        s[t] += x;
        __syncthreads();
    }
    int p = s[t] - tsum;                  // exclusive prefix of this thread
    if (t == TPB - 1) bsum[blockIdx.x] = s[TPB - 1];
    if (base + 0 < N) rowptr[base + 0] = p;  p += v0;
    if (base + 1 < N) rowptr[base + 1] = p;  p += v1;
    if (base + 2 < N) rowptr[base + 2] = p;  p += v2;
    if (base + 3 < N) rowptr[base + 3] = p;
}

// exclusive-scan bsum[nb] in place (nb <= 256), single block
__global__ __launch_bounds__(TPB) void scan2_kernel(int* __restrict__ bsum, int nb) {
    __shared__ int s[TPB];
    int t = threadIdx.x;
    int v = (t < nb) ? bsum[t] : 0;
    s[t] = v;
    __syncthreads();
    for (int off = 1; off < TPB; off <<= 1) {
        int x = (t >= off) ? s[t - off] : 0;
        __syncthreads();
        s[t] += x;
        __syncthreads();
    }
    if (t < nb) bsum[t] = s[t] - v;
}

// add block offsets; mirror rowptr into cnt (running cursors)
__global__ __launch_bounds__(TPB) void scan3_kernel(int* __restrict__ rowptr,
                                                    int* __restrict__ cnt,
                                                    const int* __restrict__ bsum,
                                                    int N) {
    int i = blockIdx.x * TPB + threadIdx.x;
    if (i < N) {
        int r = rowptr[i] + bsum[i >> 10];
        rowptr[i] = r;
        cnt[i]    = r;
    }
}

// dst-sorted permutation of edge ids
__global__ __launch_bounds__(TPB) void reorder_kernel(const int* __restrict__ dst,
                                                      int* __restrict__ cnt,
                                                      int* __restrict__ perm, int E) {
    int e = blockIdx.x * TPB + threadIdx.x;
    if (e >= E) return;
    int pos = atomicAdd(&cnt[dst[e]], 1);
    perm[pos] = e;
}

// h1[N,32] = x[N,128] @ W[128,32].  Block: 32 nodes, 256 threads.
__global__ __launch_bounds__(TPB) void gemm1_kernel(const float* __restrict__ x,
                                                    const float* __restrict__ W,
                                                    float* __restrict__ h, int N) {
    __shared__ float Ws[128 * 32];     // 16 KB
    __shared__ float xs[32 * 129];     // padded stride to kill bank conflicts
    const int tid = threadIdx.x;
    const int nb  = blockIdx.x * 32;

    const float4* W4  = (const float4*)W;
    float4*       Ws4 = (float4*)Ws;
#pragma unroll
    for (int i = 0; i < 4; ++i) Ws4[tid + i * 256] = W4[tid + i * 256];

#pragma unroll
    for (int i = 0; i < 4; ++i) {
        int idx  = tid + i * 256;      // float4 index within the 32x128 tile
        int node = idx >> 5;
        int col4 = idx & 31;
        if (nb + node < N) {
            float4 v = ((const float4*)(x + (size_t)nb * 128))[idx];
            float* p = &xs[node * 129 + col4 * 4];
            p[0] = v.x; p[1] = v.y; p[2] = v.z; p[3] = v.w;
        }
    }
    __syncthreads();

    const int nl = tid >> 3;
    const int og = (tid & 7) * 4;
    float a0 = 0.f, a1 = 0.f, a2 = 0.f, a3 = 0.f;
#pragma unroll 8
    for (int k = 0; k < 128; ++k) {
        float xv = xs[nl * 129 + k];
        const float* wp = &Ws[k * 32 + og];
        a0 = fmaf(xv, wp[0], a0);
        a1 = fmaf(xv, wp[1], a1);
        a2 = fmaf(xv, wp[2], a2);
        a3 = fmaf(xv, wp[3], a3);
    }
    int node = nb + nl;
    if (node < N) {
        float* out = &h[(size_t)node * 32 + og];
        out[0] = a0; out[1] = a1; out[2] = a2; out[3] = a3;
    }
}

// conv1 aggregate: one wave per node; lane = (eh=lane>>5, f=lane&31)
// hout[d,f] = relu( dinv[d]*sum_e dinv[s]*w*h1[s,f] + h1[d,f]/deg + b[f] )
__global__ __launch_bounds__(TPB) void gather32_kernel(const int* __restrict__ rowptr,
                                                       const int* __restrict__ perm,
                                                       const int* __restrict__ src,
                                                       const float* __restrict__ ew,
                                                       const float* __restrict__ dinv,
                                                       const float* __restrict__ h1,
                                                       const float* __restrict__ b,
                                                       float* __restrict__ hout,
                                                       int N, int E) {
    int wave = (blockIdx.x * TPB + threadIdx.x) >> 6;
    int lane = threadIdx.x & 63;
    if (wave >= N) return;
    const int d  = wave;
    const int f  = lane & 31;
    const int eh = lane >> 5;                 // 0,1
    const int begin = rowptr[d];
    const int end   = (d == N - 1) ? E : rowptr[d + 1];
    float acc = 0.f;
    for (int i = begin + eh; i < end; i += 2) {
        int p = perm[i];
        int s = src[p];
        float nm = dinv[s] * ew[p];
        acc = fmaf(nm, h1[(size_t)s * 32 + f], acc);
    }
    acc += __shfl_xor(acc, 32);               // combine the two edge halves
    if (eh == 0) {
        float di = dinv[d];
        float v  = acc * di + h1[(size_t)d * 32 + f] * di * di + b[f];
        hout[(size_t)d * 32 + f] = fmaxf(v, 0.f);
    }
}

// h2[N,16] = h[N,32] @ W2[32,16]; thread per (node, f)
__global__ __launch_bounds__(TPB) void gemm2_kernel(const float* __restrict__ h,
                                                    const float* __restrict__ W,
                                                    float* __restrict__ out, int N) {
    __shared__ float Ws[32 * 16];
    int tid = threadIdx.x;
    if (tid < 128) ((float4*)Ws)[tid] = ((const float4*)W)[tid];
    __syncthreads();
    int idx  = blockIdx.x * TPB + tid;
    int node = idx >> 4;
    int f    = idx & 15;
    if (node >= N) return;
    const float* hr = &h[(size_t)node * 32];
    float acc = 0.f;
#pragma unroll
    for (int k = 0; k < 32; ++k) acc = fmaf(hr[k], Ws[k * 16 + f], acc);
    out[(size_t)node * 16 + f] = acc;
}

// conv2 aggregate fused with both FC heads. One wave per node.
__global__ __launch_bounds__(TPB) void gather16_final_kernel(
        const int* __restrict__ rowptr, const int* __restrict__ perm,
        const int* __restrict__ src, const float* __restrict__ ew,
        const float* __restrict__ dinv, const float* __restrict__ h2,
        const float* __restrict__ h, const float* __restrict__ b2,
        const float* __restrict__ fc1_w, const float* __restrict__ fc1_b,
        const float* __restrict__ fc2_w, const float* __restrict__ fc2_b,
        float* __restrict__ out, int N, int E) {
    int wave = (blockIdx.x * TPB + threadIdx.x) >> 6;
    int lane = threadIdx.x & 63;
    if (wave >= N) return;
    const int d  = wave;
    const int f  = lane & 15;
    const int eh = lane >> 4;                 // 0..3
    const int begin = rowptr[d];
    const int end   = (d == N - 1) ? E : rowptr[d + 1];
    float acc = 0.f;
    for (int i = begin + eh; i < end; i += 4) {
        int p = perm[i];
        int s = src[p];
        acc = fmaf(dinv[s] * ew[p], h2[(size_t)s * 16 + f], acc);
    }
    acc += __shfl_xor(acc, 16);
    acc += __shfl_xor(acc, 32);               // all eh groups hold full sum

    float di = dinv[d];
    float x2 = acc * di + h2[(size_t)d * 16 + f] * di * di + b2[f];

    float p = x2 * fc1_w[f];                  // dot over 16 feats
    p += __shfl_xor(p, 1);
    p += __shfl_xor(p, 2);
    p += __shfl_xor(p, 4);
    p += __shfl_xor(p, 8);
    float x1f = p + fc1_b[0];
    float c   = 1.0f / (1.0f + expf(-x1f));

    float q = (lane < 32) ? h[(size_t)d * 32 + lane] * fc2_w[lane] : 0.f;
    q += __shfl_xor(q, 1);
    q += __shfl_xor(q, 2);
    q += __shfl_xor(q, 4);
    q += __shfl_xor(q, 8);
    q += __shfl_xor(q, 16);
    q += __shfl_xor(q, 32);

    if (lane == 0) {
        out[d]     = q + c * fc2_w[32] + fc2_b[0];
        out[N + d] = x1f;
    }
}

extern "C" void kernel_launch(void* const* d_in, const int* in_sizes, int n_in,
                              void* d_out, int out_size, void* d_ws, size_t ws_size,
                              hipStream_t stream) {
    const float* x     = (const float*)d_in[0];
    const int*   ei    = (const int*)d_in[1];
    const float* ew    = (const float*)d_in[2];
    const float* W1    = (const float*)d_in[3];
    const float* b1    = (const float*)d_in[4];
    const float* W2    = (const float*)d_in[5];
    const float* b2    = (const float*)d_in[6];
    const float* fc1_w = (const float*)d_in[7];
    const float* fc1_b = (const float*)d_in[8];
    const float* fc2_w = (const float*)d_in[9];
    const float* fc2_b = (const float*)d_in[10];

    const int N = in_sizes[0] / 128;
    const int E = in_sizes[2];
    const int* src = ei;
    const int* dst = ei + E;

    // workspace (4B units, total E + 65N = 9.7M = 38.8 MB):
    // perm[E] | h1[32N] | h[32N] | deg[N] | rowptr[N]
    // aliases: h2[16N] := h1 (h1 dead after gather32);
    //          cnt[N], bsum[256] := start of h (dead before gather32 writes h)
    int*   perm   = (int*)d_ws;
    float* h1     = (float*)d_ws + E;
    float* h      = h1 + (size_t)32 * N;
    float* deg    = h + (size_t)32 * N;
    int*   rowptr = (int*)(deg + N);
    int*   cnt    = (int*)h;
    int*   bsum   = cnt + N;
    float* h2     = h1;

    hipMemsetAsync(deg, 0, (size_t)N * sizeof(float), stream);
    hipMemsetAsync(cnt, 0, (size_t)N * sizeof(int), stream);

    hist_kernel<<<(E + TPB - 1) / TPB, TPB, 0, stream>>>(dst, ew, cnt, deg, E);
    gemm1_kernel<<<(N + 31) / 32, TPB, 0, stream>>>(x, W1, h1, N);

    const int nb = (N + 1023) / 1024;   // <=256 blocks for scan2
    scan1_kernel<<<nb, TPB, 0, stream>>>(cnt, rowptr, bsum, N);
    scan2_kernel<<<1, TPB, 0, stream>>>(bsum, nb);
    scan3_kernel<<<(N + TPB - 1) / TPB, TPB, 0, stream>>>(rowptr, cnt, bsum, N);

    dinv_kernel<<<(N + TPB - 1) / TPB, TPB, 0, stream>>>(deg, N);
    reorder_kernel<<<(E + TPB - 1) / TPB, TPB, 0, stream>>>(dst, cnt, perm, E);

    gather32_kernel<<<(N + 3) / 4, TPB, 0, stream>>>(rowptr, perm, src, ew, deg,
                                                     h1, b1, h, N, E);
    gemm2_kernel<<<((N * 16) + TPB - 1) / TPB, TPB, 0, stream>>>(h, W2, h2, N);
    gather16_final_kernel<<<(N + 3) / 4, TPB, 0, stream>>>(
        rowptr, perm, src, ew, deg, h2, h, b2, fc1_w, fc1_b, fc2_w, fc2_b,
        (float*)d_out, N, E);
}

// Round 4
// 1125.251 us; speedup vs baseline: 1.0114x; 1.0114x over previous
//
#include <hip/hip_runtime.h>
#include <math.h>

// ---------------------------------------------------------------------------
// GCN, CSR-gather for conv1, scalar-ized conv2:
//   x1f = dinv*[sum_e dinv[s]*w*g[s]] + g[d]/deg + dot(b2,fc1_w) + fc1_b,
//   where g = h @ (W2 @ fc1_w)  -- conv2's 16-dim aggregation collapses to 1.
// CSR build writes perm[] with atomicExch (dword-granular at LLC; plain
// scattered stores cost a 64B line writeback each -- measured R3: 194 MB).
// Workspace = E + 66N floats, identical to R3's proven-safe footprint:
//   perm[E] | h1[32N] | h[32N] | deg[N] | rowptr[N]
//   cnt/bsum alias h (dead before gather32 writes h);
//   g[N], aggg[N] alias h1 (dead after gather32).
// Outputs (concat): r[N], x1f[N]
// ---------------------------------------------------------------------------

#define TPB 256

__device__ __forceinline__ float atomAddF(float* p, float v) {
    return unsafeAtomicAdd(p, v);   // native global_atomic_add_f32 on gfx950
}

// cnt[dst]++ ; deg[dst] += w
__global__ __launch_bounds__(TPB) void hist_kernel(const int* __restrict__ dst,
                                                   const float* __restrict__ ew,
                                                   int* __restrict__ cnt,
                                                   float* __restrict__ deg, int E) {
    int e = blockIdx.x * TPB + threadIdx.x;
    if (e < E) {
        int d = dst[e];
        atomicAdd(&cnt[d], 1);
        atomAddF(&deg[d], ew[e]);
    }
}

// deg -> dinv = 1/sqrt(deg+1)  (in place)
__global__ __launch_bounds__(TPB) void dinv_kernel(float* __restrict__ deg, int N) {
    int i = blockIdx.x * TPB + threadIdx.x;
    if (i < N) deg[i] = 1.0f / sqrtf(deg[i] + 1.0f);
}

// ---- 3-kernel exclusive scan over cnt[N] -> rowptr[N] ---------------------
__global__ __launch_bounds__(TPB) void scan1_kernel(const int* __restrict__ cnt,
                                                    int* __restrict__ rowptr,
                                                    int* __restrict__ bsum, int N) {
    __shared__ int s[TPB];
    int t = threadIdx.x;
    int base = blockIdx.x * 1024 + t * 4;
    int v0 = 0, v1 = 0, v2 = 0, v3 = 0;
    if (base + 0 < N) v0 = cnt[base + 0];
    if (base + 1 < N) v1 = cnt[base + 1];
    if (base + 2 < N) v2 = cnt[base + 2];
    if (base + 3 < N) v3 = cnt[base + 3];
    int tsum = v0 + v1 + v2 + v3;
    s[t] = tsum;
    __syncthreads();
    for (int off = 1; off < TPB; off <<= 1) {
        int x = (t >= off) ? s[t - off] : 0;
        __syncthreads();
        s[t] += x;
        __syncthreads();
    }
    int p = s[t] - tsum;                  // exclusive prefix of this thread
    if (t == TPB - 1) bsum[blockIdx.x] = s[TPB - 1];
    if (base + 0 < N) rowptr[base + 0] = p;  p += v0;
    if (base + 1 < N) rowptr[base + 1] = p;  p += v1;
    if (base + 2 < N) rowptr[base + 2] = p;  p += v2;
    if (base + 3 < N) rowptr[base + 3] = p;
}

// exclusive-scan bsum[nb] in place (nb <= 256), single block
__global__ __launch_bounds__(TPB) void scan2_kernel(int* __restrict__ bsum, int nb) {
    __shared__ int s[TPB];
    int t = threadIdx.x;
    int v = (t < nb) ? bsum[t] : 0;
    s[t] = v;
    __syncthreads();
    for (int off = 1; off < TPB; off <<= 1) {
        int x = (t >= off) ? s[t - off] : 0;
        __syncthreads();
        s[t] += x;
        __syncthreads();
    }
    if (t < nb) bsum[t] = s[t] - v;
}

// add block offsets; mirror rowptr into cnt (running cursors)
__global__ __launch_bounds__(TPB) void scan3_kernel(int* __restrict__ rowptr,
                                                    int* __restrict__ cnt,
                                                    const int* __restrict__ bsum,
                                                    int N) {
    int i = blockIdx.x * TPB + threadIdx.x;
    if (i < N) {
        int r = rowptr[i] + bsum[i >> 10];
        rowptr[i] = r;
        cnt[i]    = r;
    }
}

// dst-sorted permutation of edge ids; atomicExch keeps the scattered write
// dword-granular at the LLC (plain store = 64B line writeback, measured R3)
__global__ __launch_bounds__(TPB) void reorder_kernel(const int* __restrict__ dst,
                                                      int* __restrict__ cnt,
                                                      int* __restrict__ perm, int E) {
    int e = blockIdx.x * TPB + threadIdx.x;
    if (e >= E) return;
    int pos = atomicAdd(&cnt[dst[e]], 1);
    atomicExch(&perm[pos], e);
}

// h1[N,32] = x[N,128] @ W[128,32].  Block: 32 nodes, 256 threads.
__global__ __launch_bounds__(TPB) void gemm1_kernel(const float* __restrict__ x,
                                                    const float* __restrict__ W,
                                                    float* __restrict__ h, int N) {
    __shared__ float Ws[128 * 32];     // 16 KB
    __shared__ float xs[32 * 129];     // padded stride to kill bank conflicts
    const int tid = threadIdx.x;
    const int nb  = blockIdx.x * 32;

    const float4* W4  = (const float4*)W;
    float4*       Ws4 = (float4*)Ws;
#pragma unroll
    for (int i = 0; i < 4; ++i) Ws4[tid + i * 256] = W4[tid + i * 256];

#pragma unroll
    for (int i = 0; i < 4; ++i) {
        int idx  = tid + i * 256;      // float4 index within the 32x128 tile
        int node = idx >> 5;
        int col4 = idx & 31;
        if (nb + node < N) {
            float4 v = ((const float4*)(x + (size_t)nb * 128))[idx];
            float* p = &xs[node * 129 + col4 * 4];
            p[0] = v.x; p[1] = v.y; p[2] = v.z; p[3] = v.w;
        }
    }
    __syncthreads();

    const int nl = tid >> 3;
    const int og = (tid & 7) * 4;
    float a0 = 0.f, a1 = 0.f, a2 = 0.f, a3 = 0.f;
#pragma unroll 8
    for (int k = 0; k < 128; ++k) {
        float xv = xs[nl * 129 + k];
        const float* wp = &Ws[k * 32 + og];
        a0 = fmaf(xv, wp[0], a0);
        a1 = fmaf(xv, wp[1], a1);
        a2 = fmaf(xv, wp[2], a2);
        a3 = fmaf(xv, wp[3], a3);
    }
    int node = nb + nl;
    if (node < N) {
        float* out = &h[(size_t)node * 32 + og];
        out[0] = a0; out[1] = a1; out[2] = a2; out[3] = a3;
    }
}

// conv1 aggregate + bias + relu fused: one wave per node
// h[d,f] = relu( dinv[d]*sum_e dinv[s]*w*h1[s,f] + h1[d,f]*dinv^2 + b[f] )
__global__ __launch_bounds__(TPB) void gather32_kernel(const int* __restrict__ rowptr,
                                                       const int* __restrict__ perm,
                                                       const int* __restrict__ src,
                                                       const float* __restrict__ ew,
                                                       const float* __restrict__ dinv,
                                                       const float* __restrict__ h1,
                                                       const float* __restrict__ b,
                                                       float* __restrict__ hout,
                                                       int N, int E) {
    int wave = (blockIdx.x * TPB + threadIdx.x) >> 6;
    int lane = threadIdx.x & 63;
    if (wave >= N) return;
    const int d  = wave;
    const int f  = lane & 31;
    const int eh = lane >> 5;                 // 0,1
    const int begin = rowptr[d];
    const int end   = (d == N - 1) ? E : rowptr[d + 1];
    float acc = 0.f;
    for (int i = begin + eh; i < end; i += 2) {
        int p = perm[i];
        int s = src[p];
        float nm = dinv[s] * ew[p];
        acc = fmaf(nm, h1[(size_t)s * 32 + f], acc);
    }
    acc += __shfl_xor(acc, 32);               // combine the two edge halves
    if (eh == 0) {
        float di = dinv[d];
        float v  = acc * di + h1[(size_t)d * 32 + f] * di * di + b[f];
        hout[(size_t)d * 32 + f] = fmaxf(v, 0.f);
    }
}

// g[i] = h[i,:] . (W2 @ fc1_w)   (wv computed per block in LDS)
__global__ __launch_bounds__(TPB) void gvec_kernel(const float* __restrict__ h,
                                                   const float* __restrict__ W2,
                                                   const float* __restrict__ fc1_w,
                                                   float* __restrict__ g, int N) {
    __shared__ float wv[32];
    int t = threadIdx.x;
    if (t < 32) {
        float a = 0.f;
#pragma unroll
        for (int j = 0; j < 16; ++j) a = fmaf(W2[t * 16 + j], fc1_w[j], a);
        wv[t] = a;
    }
    __syncthreads();
    int i = blockIdx.x * TPB + t;
    if (i >= N) return;
    const float* hr = &h[(size_t)i * 32];
    float a = 0.f;
#pragma unroll
    for (int k = 0; k < 32; ++k) a = fmaf(hr[k], wv[k], a);
    g[i] = a;
}

// aggg[dst] += dinv[src]*w*g[src]   (one scalar atomic per edge)
__global__ __launch_bounds__(TPB) void scatter1_kernel(const int* __restrict__ src,
                                                       const int* __restrict__ dst,
                                                       const float* __restrict__ ew,
                                                       const float* __restrict__ dinv,
                                                       const float* __restrict__ g,
                                                       float* __restrict__ aggg, int E) {
    int e = blockIdx.x * TPB + threadIdx.x;
    if (e >= E) return;
    int s = src[e];
    atomAddF(&aggg[dst[e]], dinv[s] * ew[e] * g[s]);
}

// x1f = dinv*aggg + g*dinv^2 + dot(b2,fc1_w) + fc1_b;  c = sigmoid(x1f);
// r = h[d,:].fc2_w[0:32] + c*fc2_w[32] + fc2_b
__global__ __launch_bounds__(TPB) void final_kernel(const float* __restrict__ h,
                                                    const float* __restrict__ g,
                                                    const float* __restrict__ aggg,
                                                    const float* __restrict__ dinv,
                                                    const float* __restrict__ b2,
                                                    const float* __restrict__ fc1_w,
                                                    const float* __restrict__ fc1_b,
                                                    const float* __restrict__ fc2_w,
                                                    const float* __restrict__ fc2_b,
                                                    float* __restrict__ out, int N) {
    int i = blockIdx.x * TPB + threadIdx.x;
    if (i >= N) return;
    float cst = fc1_b[0];
#pragma unroll
    for (int j = 0; j < 16; ++j) cst = fmaf(b2[j], fc1_w[j], cst);
    float di  = dinv[i];
    float x1f = aggg[i] * di + g[i] * di * di + cst;
    float c   = 1.0f / (1.0f + expf(-x1f));
    const float* hr = &h[(size_t)i * 32];
    float r = fmaf(c, fc2_w[32], fc2_b[0]);
#pragma unroll
    for (int k = 0; k < 32; ++k) r = fmaf(hr[k], fc2_w[k], r);
    out[i]     = r;
    out[N + i] = x1f;
}

extern "C" void kernel_launch(void* const* d_in, const int* in_sizes, int n_in,
                              void* d_out, int out_size, void* d_ws, size_t ws_size,
                              hipStream_t stream) {
    const float* x     = (const float*)d_in[0];
    const int*   ei    = (const int*)d_in[1];
    const float* ew    = (const float*)d_in[2];
    const float* W1    = (const float*)d_in[3];
    const float* b1    = (const float*)d_in[4];
    const float* W2    = (const float*)d_in[5];
    const float* b2    = (const float*)d_in[6];
    const float* fc1_w = (const float*)d_in[7];
    const float* fc1_b = (const float*)d_in[8];
    const float* fc2_w = (const float*)d_in[9];
    const float* fc2_b = (const float*)d_in[10];

    const int N = in_sizes[0] / 128;
    const int E = in_sizes[2];
    const int* src = ei;
    const int* dst = ei + E;

    // workspace (4B units, E + 66N total — R3-proven footprint):
    // perm[E] | h1[32N] | h[32N] | deg[N] | rowptr[N]
    // aliases: cnt[N],bsum[256] := h (dead before gather32 writes h)
    //          g[N] := h1[0..N), aggg[N] := h1[N..2N)  (h1 dead after gather32)
    int*   perm   = (int*)d_ws;
    float* h1     = (float*)d_ws + E;
    float* h      = h1 + (size_t)32 * N;
    float* deg    = h + (size_t)32 * N;
    int*   rowptr = (int*)(deg + N);
    int*   cnt    = (int*)h;
    int*   bsum   = cnt + N;
    float* g      = h1;
    float* aggg   = h1 + N;

    hipMemsetAsync(deg, 0, (size_t)N * sizeof(float), stream);
    hipMemsetAsync(cnt, 0, (size_t)N * sizeof(int), stream);

    hist_kernel<<<(E + TPB - 1) / TPB, TPB, 0, stream>>>(dst, ew, cnt, deg, E);
    gemm1_kernel<<<(N + 31) / 32, TPB, 0, stream>>>(x, W1, h1, N);

    const int nb = (N + 1023) / 1024;   // <=256 blocks for scan2
    scan1_kernel<<<nb, TPB, 0, stream>>>(cnt, rowptr, bsum, N);
    scan2_kernel<<<1, TPB, 0, stream>>>(bsum, nb);
    scan3_kernel<<<(N + TPB - 1) / TPB, TPB, 0, stream>>>(rowptr, cnt, bsum, N);

    dinv_kernel<<<(N + TPB - 1) / TPB, TPB, 0, stream>>>(deg, N);
    reorder_kernel<<<(E + TPB - 1) / TPB, TPB, 0, stream>>>(dst, cnt, perm, E);

    gather32_kernel<<<(N + 3) / 4, TPB, 0, stream>>>(rowptr, perm, src, ew, deg,
                                                     h1, b1, h, N, E);

    // h1 is dead now; reuse its space for g and aggg
    hipMemsetAsync(aggg, 0, (size_t)N * sizeof(float), stream);
    gvec_kernel<<<(N + TPB - 1) / TPB, TPB, 0, stream>>>(h, W2, fc1_w, g, N);
    scatter1_kernel<<<(E + TPB - 1) / TPB, TPB, 0, stream>>>(src, dst, ew, deg, g,
                                                             aggg, E);
    final_kernel<<<(N + TPB - 1) / TPB, TPB, 0, stream>>>(
        h, g, aggg, deg, b2, fc1_w, fc1_b, fc2_w, fc2_b, (float*)d_out, N);
}

// Round 5
// 1016.067 us; speedup vs baseline: 1.1201x; 1.1075x over previous
//
#include <hip/hip_runtime.h>
#include <hip/hip_bf16.h>
#include <math.h>

// ---------------------------------------------------------------------------
// GCN, fully binned (counting-sort by dst bucket), ZERO global atomics and
// ZERO scattered dword writes (both measured 100-330us per E-scale kernel).
// Random reads only into L2-resident tables (dinv, g: 400KB) or LLC-resident
// bf16 h1 rows (6.4MB, 64B/row coalesced).
//   payload[e] (u64) = [ (dst&127)<<17 | src ]<<32 | bits(ew)
//   bucket = dst>>7 (128 nodes/bucket), nbk=782; binned bucket-major,
//   per-(bucket,block) segments from scanned histogram (deterministic).
// Pipeline: gemm1(bf16 out) | binhist -> scan -> binwrite | deg_bin ->
//           agg1 (conv1+relu+g+rpart fused) -> agg2 (conv2+fc heads fused)
// Outputs: out[0..N)=r, out[N..2N)=x1f
// ---------------------------------------------------------------------------

#define TPB 256
#define NB 128            // nodes per bucket (dl fits 7 bits)
#define CHUNK 16384       // edges per binning block
#define MAXBK 800         // >= nbk = ceil(100000/128) = 782

typedef unsigned long long u64;
typedef unsigned int u32;
typedef unsigned short u16;

__device__ __forceinline__ u16 f32_to_bf16(float x) {
    u32 u = __float_as_uint(x);
    u += 0x7FFF + ((u >> 16) & 1);   // round to nearest even
    return (u16)(u >> 16);
}
__device__ __forceinline__ float bf16_to_f32(u16 v) {
    return __uint_as_float(((u32)v) << 16);
}

// h1b[N,32] (bf16) = x[N,128] @ W[128,32].  Block: 32 nodes, 256 threads.
__global__ __launch_bounds__(TPB) void gemm1_kernel(const float* __restrict__ x,
                                                    const float* __restrict__ W,
                                                    u16* __restrict__ h1b, int N) {
    __shared__ float Ws[128 * 32];
    __shared__ float xs[32 * 129];
    const int tid = threadIdx.x;
    const int nb  = blockIdx.x * 32;

    const float4* W4  = (const float4*)W;
    float4*       Ws4 = (float4*)Ws;
#pragma unroll
    for (int i = 0; i < 4; ++i) Ws4[tid + i * 256] = W4[tid + i * 256];

#pragma unroll
    for (int i = 0; i < 4; ++i) {
        int idx  = tid + i * 256;
        int node = idx >> 5;
        int col4 = idx & 31;
        if (nb + node < N) {
            float4 v = ((const float4*)(x + (size_t)nb * 128))[idx];
            float* p = &xs[node * 129 + col4 * 4];
            p[0] = v.x; p[1] = v.y; p[2] = v.z; p[3] = v.w;
        }
    }
    __syncthreads();

    const int nl = tid >> 3;
    const int og = (tid & 7) * 4;
    float a0 = 0.f, a1 = 0.f, a2 = 0.f, a3 = 0.f;
#pragma unroll 8
    for (int k = 0; k < 128; ++k) {
        float xv = xs[nl * 129 + k];
        const float* wp = &Ws[k * 32 + og];
        a0 = fmaf(xv, wp[0], a0);
        a1 = fmaf(xv, wp[1], a1);
        a2 = fmaf(xv, wp[2], a2);
        a3 = fmaf(xv, wp[3], a3);
    }
    int node = nb + nl;
    if (node < N) {
        u16* o = &h1b[(size_t)node * 32 + og];
        o[0] = f32_to_bf16(a0); o[1] = f32_to_bf16(a1);
        o[2] = f32_to_bf16(a2); o[3] = f32_to_bf16(a3);
    }
}

// Phase R1: per-(bucket, block) histogram. bh[b*nrb + blk] = count.
__global__ __launch_bounds__(TPB) void binhist_kernel(const int* __restrict__ dst,
                                                      int* __restrict__ bh,
                                                      int E, int nbk, int nrb) {
    __shared__ int hist[MAXBK];
    const int t = threadIdx.x, blk = blockIdx.x;
    const int base = blk * CHUNK;
    const int cA = min(CHUNK, E - base);
    for (int i = t; i < nbk; i += TPB) hist[i] = 0;
    __syncthreads();
    for (int k = t; k < cA; k += TPB) atomicAdd(&hist[dst[base + k] >> 7], 1);
    __syncthreads();
    for (int i = t; i < nbk; i += TPB) bh[i * nrb + blk] = hist[i];
}

// ---- 3-kernel exclusive scan over bh[TOT] in place ------------------------
__global__ __launch_bounds__(TPB) void scan1_kernel(int* bh, int* __restrict__ bsum,
                                                    int TOT) {
    __shared__ int s[TPB];
    int t = threadIdx.x;
    int base = blockIdx.x * 1024 + t * 4;
    int v0 = 0, v1 = 0, v2 = 0, v3 = 0;
    if (base + 0 < TOT) v0 = bh[base + 0];
    if (base + 1 < TOT) v1 = bh[base + 1];
    if (base + 2 < TOT) v2 = bh[base + 2];
    if (base + 3 < TOT) v3 = bh[base + 3];
    int tsum = v0 + v1 + v2 + v3;
    s[t] = tsum;
    __syncthreads();
    for (int off = 1; off < TPB; off <<= 1) {
        int x = (t >= off) ? s[t - off] : 0;
        __syncthreads();
        s[t] += x;
        __syncthreads();
    }
    int p = s[t] - tsum;
    if (t == TPB - 1) bsum[blockIdx.x] = s[TPB - 1];
    if (base + 0 < TOT) bh[base + 0] = p;  p += v0;
    if (base + 1 < TOT) bh[base + 1] = p;  p += v1;
    if (base + 2 < TOT) bh[base + 2] = p;  p += v2;
    if (base + 3 < TOT) bh[base + 3] = p;
}

__global__ __launch_bounds__(TPB) void scan2_kernel(int* __restrict__ bsum, int nb) {
    __shared__ int s[TPB];
    int t = threadIdx.x;
    int v = (t < nb) ? bsum[t] : 0;
    s[t] = v;
    __syncthreads();
    for (int off = 1; off < TPB; off <<= 1) {
        int x = (t >= off) ? s[t - off] : 0;
        __syncthreads();
        s[t] += x;
        __syncthreads();
    }
    if (t < nb) bsum[t] = s[t] - v;
}

__global__ __launch_bounds__(TPB) void scan3_kernel(int* bh,
                                                    const int* __restrict__ bsum,
                                                    int TOT) {
    int i = blockIdx.x * TPB + threadIdx.x;
    if (i < TOT) bh[i] += bsum[i >> 10];
}

// Phase R2: local counting-sort in LDS, then wave-contiguous payload writes.
__global__ __launch_bounds__(TPB) void binwrite_kernel(const int* __restrict__ dst,
                                                       const int* __restrict__ src,
                                                       const float* __restrict__ ew,
                                                       const int* __restrict__ bh,
                                                       u64* __restrict__ payload,
                                                       int E, int nbk, int nrb) {
    __shared__ u16 lperm[CHUNK];
    __shared__ u16 bpos[CHUNK];
    __shared__ int lofs[MAXBK];   // hist -> exclusive scan, in place
    __shared__ int lcnt[MAXBK];
    __shared__ int gbase[MAXBK];
    __shared__ int stmp[TPB];
    __shared__ int carry_s;

    const int t = threadIdx.x, blk = blockIdx.x;
    const int base = blk * CHUNK;
    const int cA = min(CHUNK, E - base);

    for (int i = t; i < nbk; i += TPB) { lofs[i] = 0; lcnt[i] = 0; }
    if (t == 0) carry_s = 0;
    __syncthreads();

    // A: histogram
    for (int k = t; k < cA; k += TPB) atomicAdd(&lofs[dst[base + k] >> 7], 1);
    // C-pre: load global segment bases
    for (int i = t; i < nbk; i += TPB) gbase[i] = bh[i * nrb + blk];
    __syncthreads();

    // B: exclusive scan of lofs[0..nbk) in 256-chunks with carry
    for (int c0 = 0; c0 < nbk; c0 += TPB) {
        int idx = c0 + t;
        int v = (idx < nbk) ? lofs[idx] : 0;
        stmp[t] = v;
        __syncthreads();
        for (int off = 1; off < TPB; off <<= 1) {
            int x = (t >= off) ? stmp[t - off] : 0;
            __syncthreads();
            stmp[t] += x;
            __syncthreads();
        }
        int excl = stmp[t] - v;
        int tot  = stmp[TPB - 1];
        int cb   = carry_s;
        __syncthreads();
        if (idx < nbk) lofs[idx] = excl + cb;
        if (t == 0) carry_s = cb + tot;
        __syncthreads();
    }

    // D: assign local sorted positions
    for (int k = t; k < cA; k += TPB) {
        int b = dst[base + k] >> 7;
        int rank = atomicAdd(&lcnt[b], 1);
        int lp = lofs[b] + rank;
        lperm[lp] = (u16)k;
        bpos[lp]  = (u16)b;
    }
    __syncthreads();

    // E: write out in sorted order -> contiguous runs per (bucket, block)
    for (int lp = t; lp < cA; lp += TPB) {
        int li = lperm[lp];
        int b  = bpos[lp];
        int e  = base + li;
        int d  = dst[e];
        u32 hi = ((u32)(d & (NB - 1)) << 17) | (u32)src[e];
        u64 pl = ((u64)hi << 32) | (u64)__float_as_uint(ew[e]);
        payload[gbase[b] + (lp - lofs[b])] = pl;
    }
}

// deg via LDS tile from binned payload -> dinv (no global atomics)
__global__ __launch_bounds__(TPB) void deg_bin_kernel(const u64* __restrict__ payload,
                                                      const int* __restrict__ bh,
                                                      float* __restrict__ dinv,
                                                      int N, int E, int nbk, int nrb) {
    __shared__ float dt[NB];
    const int t = threadIdx.x, b = blockIdx.x;
    if (t < NB) dt[t] = 0.f;
    __syncthreads();
    const int bstart = bh[b * nrb];
    const int bend   = (b + 1 < nbk) ? bh[(b + 1) * nrb] : E;
    for (int i = bstart + t; i < bend; i += TPB) {
        u64 pl = payload[i];
        int dl = (int)((pl >> 49) & (NB - 1));
        atomicAdd(&dt[dl], __uint_as_float((u32)pl));
    }
    __syncthreads();
    if (t < NB) {
        int n = b * NB + t;
        if (n < N) dinv[n] = rsqrtf(dt[t] + 1.0f);
    }
}

// conv1 aggregate + relu + BOTH projections fused.
// tile[dl][f] += dinv[s]*ew*h1b[s][f]; epilogue:
//   hv = relu(tile*di + h1[d]*di^2 + b1) ; g[d]=hv.wv ; rpart[d]=hv.fc2w[0:32]
__global__ __launch_bounds__(TPB) void agg1_kernel(const u64* __restrict__ payload,
                                                   const int* __restrict__ bh,
                                                   const float* __restrict__ dinv,
                                                   const u16* __restrict__ h1b,
                                                   const float* __restrict__ b1,
                                                   const float* __restrict__ W2,
                                                   const float* __restrict__ fc1_w,
                                                   const float* __restrict__ fc2_w,
                                                   float* __restrict__ g,
                                                   float* __restrict__ rpart,
                                                   int N, int E, int nbk, int nrb) {
    __shared__ float tile[NB * 32];   // 16KB
    __shared__ float wv[32];
    __shared__ float f2[32];
    const int t = threadIdx.x, b = blockIdx.x;
    for (int i = t; i < NB * 32; i += TPB) tile[i] = 0.f;
    if (t < 32) {
        float a = 0.f;
#pragma unroll
        for (int j = 0; j < 16; ++j) a = fmaf(W2[t * 16 + j], fc1_w[j], a);
        wv[t] = a;
        f2[t] = fc2_w[t];
    }
    __syncthreads();

    const int bstart = bh[b * nrb];
    const int bend   = (b + 1 < nbk) ? bh[(b + 1) * nrb] : E;
    const int wave = t >> 6, eh = (t >> 5) & 1, f = t & 31;

    int i = bstart + wave * 2 + eh;
    for (; i + 8 < bend; i += 16) {
        u64 pl0 = payload[i];
        u64 pl1 = payload[i + 8];
        u32 hi0 = (u32)(pl0 >> 32), hi1 = (u32)(pl1 >> 32);
        int s0 = hi0 & 0x1FFFF, s1 = hi1 & 0x1FFFF;
        float w0 = __uint_as_float((u32)pl0) * dinv[s0];
        float w1 = __uint_as_float((u32)pl1) * dinv[s1];
        float v0 = w0 * bf16_to_f32(h1b[(size_t)s0 * 32 + f]);
        float v1 = w1 * bf16_to_f32(h1b[(size_t)s1 * 32 + f]);
        atomicAdd(&tile[(int)((hi0 >> 17) & (NB - 1)) * 32 + f], v0);
        atomicAdd(&tile[(int)((hi1 >> 17) & (NB - 1)) * 32 + f], v1);
    }
    for (; i < bend; i += 8) {
        u64 pl = payload[i];
        u32 hi = (u32)(pl >> 32);
        int s = hi & 0x1FFFF;
        float w = __uint_as_float((u32)pl) * dinv[s];
        float v = w * bf16_to_f32(h1b[(size_t)s * 32 + f]);
        atomicAdd(&tile[(int)((hi >> 17) & (NB - 1)) * 32 + f], v);
    }
    __syncthreads();

    // epilogue: 8 half-waves x 16 rows
    const int rowgrp = t >> 5;
    for (int r = rowgrp; r < NB; r += 8) {
        int n = b * NB + r;
        if (n < N) {
            float di = dinv[n];
            float selfv = bf16_to_f32(h1b[(size_t)n * 32 + f]);
            float hv = tile[r * 32 + f] * di + selfv * di * di + b1[f];
            hv = fmaxf(hv, 0.f);
            float a = hv * wv[f];
            float c = hv * f2[f];
#pragma unroll
            for (int m = 1; m < 32; m <<= 1) {
                a += __shfl_xor(a, m);
                c += __shfl_xor(c, m);
            }
            if (f == 0) { g[n] = a; rpart[n] = c; }
        }
    }
}

// conv2 (scalar) + fc heads fused. st[dl] += dinv[s]*ew*g[s]; epilogue:
//   x1f = st*di + g[d]*di^2 + cst; c = sigmoid; r = rpart + c*fc2w[32] + fc2b
__global__ __launch_bounds__(TPB) void agg2_kernel(const u64* __restrict__ payload,
                                                   const int* __restrict__ bh,
                                                   const float* __restrict__ dinv,
                                                   const float* __restrict__ g,
                                                   const float* __restrict__ rpart,
                                                   const float* __restrict__ b2,
                                                   const float* __restrict__ fc1_w,
                                                   const float* __restrict__ fc1_b,
                                                   const float* __restrict__ fc2_w,
                                                   const float* __restrict__ fc2_b,
                                                   float* __restrict__ out,
                                                   int N, int E, int nbk, int nrb) {
    __shared__ float st[NB];
    const int t = threadIdx.x, b = blockIdx.x;
    if (t < NB) st[t] = 0.f;
    __syncthreads();
    const int bstart = bh[b * nrb];
    const int bend   = (b + 1 < nbk) ? bh[(b + 1) * nrb] : E;
    for (int i = bstart + t; i < bend; i += TPB) {
        u64 pl = payload[i];
        u32 hi = (u32)(pl >> 32);
        int s = hi & 0x1FFFF;
        float val = __uint_as_float((u32)pl) * dinv[s] * g[s];
        atomicAdd(&st[(int)((hi >> 17) & (NB - 1))], val);
    }
    __syncthreads();
    if (t < NB) {
        int n = b * NB + t;
        if (n < N) {
            float cst = fc1_b[0];
#pragma unroll
            for (int j = 0; j < 16; ++j) cst = fmaf(b2[j], fc1_w[j], cst);
            float di  = dinv[n];
            float x1f = st[t] * di + g[n] * di * di + cst;
            float c   = 1.0f / (1.0f + expf(-x1f));
            out[n]     = rpart[n] + c * fc2_w[32] + fc2_b[0];
            out[N + n] = x1f;
        }
    }
}

extern "C" void kernel_launch(void* const* d_in, const int* in_sizes, int n_in,
                              void* d_out, int out_size, void* d_ws, size_t ws_size,
                              hipStream_t stream) {
    const float* x     = (const float*)d_in[0];
    const int*   ei    = (const int*)d_in[1];
    const float* ew    = (const float*)d_in[2];
    const float* W1    = (const float*)d_in[3];
    const float* b1    = (const float*)d_in[4];
    const float* W2    = (const float*)d_in[5];
    const float* b2    = (const float*)d_in[6];
    const float* fc1_w = (const float*)d_in[7];
    const float* fc1_b = (const float*)d_in[8];
    const float* fc2_w = (const float*)d_in[9];
    const float* fc2_b = (const float*)d_in[10];

    const int N = in_sizes[0] / 128;
    const int E = in_sizes[2];
    const int* src = ei;
    const int* dst = ei + E;

    const int nbk = (N + NB - 1) / NB;            // 782 (requires < 2^17 nodes)
    const int nrb = (E + CHUNK - 1) / CHUNK;      // 196
    const int TOT = nbk * nrb;                    // 153,272

    // ws (4B units): payload 2E | h1b 16N | dinv N | g N | rpart N | bh TOT | bsum
    // total ~ 84.6N = 33.8 MB  (< 38.8 MB proven-safe)
    u64*   payload = (u64*)d_ws;
    u16*   h1b     = (u16*)((float*)d_ws + (size_t)2 * E);
    float* dinv    = (float*)d_ws + (size_t)2 * E + (size_t)16 * N;
    float* g       = dinv + N;
    float* rpart   = g + N;
    int*   bh      = (int*)(rpart + N);
    int*   bsum    = bh + TOT;

    gemm1_kernel<<<(N + 31) / 32, TPB, 0, stream>>>(x, W1, h1b, N);

    binhist_kernel<<<nrb, TPB, 0, stream>>>(dst, bh, E, nbk, nrb);
    const int nb1 = (TOT + 1023) / 1024;          // 150 <= 256
    scan1_kernel<<<nb1, TPB, 0, stream>>>(bh, bsum, TOT);
    scan2_kernel<<<1, TPB, 0, stream>>>(bsum, nb1);
    scan3_kernel<<<(TOT + TPB - 1) / TPB, TPB, 0, stream>>>(bh, bsum, TOT);
    binwrite_kernel<<<nrb, TPB, 0, stream>>>(dst, src, ew, bh, payload, E, nbk, nrb);

    deg_bin_kernel<<<nbk, TPB, 0, stream>>>(payload, bh, dinv, N, E, nbk, nrb);
    agg1_kernel<<<nbk, TPB, 0, stream>>>(payload, bh, dinv, h1b, b1, W2, fc1_w,
                                         fc2_w, g, rpart, N, E, nbk, nrb);
    agg2_kernel<<<nbk, TPB, 0, stream>>>(payload, bh, dinv, g, rpart, b2, fc1_w,
                                         fc1_b, fc2_w, fc2_b, (float*)d_out,
                                         N, E, nbk, nrb);
}

// Round 6
// 885.448 us; speedup vs baseline: 1.2853x; 1.1475x over previous
//
#include <hip/hip_runtime.h>
#include <math.h>

// ---------------------------------------------------------------------------
// GCN, fully binned, zero global atomics, zero scattered-dword stores.
// R5 post-mortem: agg1 was latency-bound (VALU 6%, HBM 1%, occ 24%).
// R6: NB=64 (2x blocks), dinv pre-folded into h1b'/g' (shortens the load
// chain to payload->h1b), 4x unrolled gathers, simplified binwrite.
//   payload[i] (u64) = [ (dst&63)<<17 | src ]<<32 | bits(ew)
//   bucket = dst>>6, nbk=1563; bucket-major, per-(bucket,chunk) segments.
// Pipeline: binhist -> scan -> binwrite -> deg_bin -> gemm1(dinv-scaled bf16)
//           -> agg1 (conv1+relu+g'+rpart fused) -> agg2 (conv2+fc heads)
// Outputs: out[0..N)=r, out[N..2N)=x1f
// ---------------------------------------------------------------------------

#define TPB 256
#define NB 64             // nodes per bucket (dl fits 6 bits)
#define CHUNK 8192        // edges per binning block
#define MAXBK 1600        // >= nbk = ceil(100000/64) = 1563

typedef unsigned long long u64;
typedef unsigned int u32;
typedef unsigned short u16;

__device__ __forceinline__ u16 f32_to_bf16(float x) {
    u32 u = __float_as_uint(x);
    u += 0x7FFF + ((u >> 16) & 1);   // round to nearest even
    return (u16)(u >> 16);
}
__device__ __forceinline__ float bf16_to_f32(u16 v) {
    return __uint_as_float(((u32)v) << 16);
}

// Phase 1: per-(bucket, chunk) histogram. bh[b*nrb + blk] = count.
__global__ __launch_bounds__(TPB) void binhist_kernel(const int* __restrict__ dst,
                                                      int* __restrict__ bh,
                                                      int E, int nbk, int nrb) {
    __shared__ int hist[MAXBK];
    const int t = threadIdx.x, blk = blockIdx.x;
    const int base = blk * CHUNK;
    const int cA = min(CHUNK, E - base);
    for (int i = t; i < nbk; i += TPB) hist[i] = 0;
    __syncthreads();
    for (int k = t; k < cA; k += TPB) atomicAdd(&hist[dst[base + k] >> 6], 1);
    __syncthreads();
    for (int i = t; i < nbk; i += TPB) bh[i * nrb + blk] = hist[i];
}

// ---- 3-kernel exclusive scan over bh[TOT] in place ------------------------
__global__ __launch_bounds__(TPB) void scan1_kernel(int* bh, int* __restrict__ bsum,
                                                    int TOT) {
    __shared__ int s[TPB];
    int t = threadIdx.x;
    int base = blockIdx.x * 1024 + t * 4;
    int v0 = 0, v1 = 0, v2 = 0, v3 = 0;
    if (base + 0 < TOT) v0 = bh[base + 0];
    if (base + 1 < TOT) v1 = bh[base + 1];
    if (base + 2 < TOT) v2 = bh[base + 2];
    if (base + 3 < TOT) v3 = bh[base + 3];
    int tsum = v0 + v1 + v2 + v3;
    s[t] = tsum;
    __syncthreads();
    for (int off = 1; off < TPB; off <<= 1) {
        int x = (t >= off) ? s[t - off] : 0;
        __syncthreads();
        s[t] += x;
        __syncthreads();
    }
    int p = s[t] - tsum;
    if (t == TPB - 1) bsum[blockIdx.x] = s[TPB - 1];
    if (base + 0 < TOT) bh[base + 0] = p;  p += v0;
    if (base + 1 < TOT) bh[base + 1] = p;  p += v1;
    if (base + 2 < TOT) bh[base + 2] = p;  p += v2;
    if (base + 3 < TOT) bh[base + 3] = p;
}

// exclusive-scan bsum[nb] in place, nb <= 1024 (4 per thread), single block
__global__ __launch_bounds__(TPB) void scan2_kernel(int* __restrict__ bsum, int nb) {
    __shared__ int s[TPB];
    int t = threadIdx.x;
    int base = t * 4;
    int v0 = (base + 0 < nb) ? bsum[base + 0] : 0;
    int v1 = (base + 1 < nb) ? bsum[base + 1] : 0;
    int v2 = (base + 2 < nb) ? bsum[base + 2] : 0;
    int v3 = (base + 3 < nb) ? bsum[base + 3] : 0;
    int tsum = v0 + v1 + v2 + v3;
    s[t] = tsum;
    __syncthreads();
    for (int off = 1; off < TPB; off <<= 1) {
        int x = (t >= off) ? s[t - off] : 0;
        __syncthreads();
        s[t] += x;
        __syncthreads();
    }
    int p = s[t] - tsum;
    if (base + 0 < nb) bsum[base + 0] = p;  p += v0;
    if (base + 1 < nb) bsum[base + 1] = p;  p += v1;
    if (base + 2 < nb) bsum[base + 2] = p;  p += v2;
    if (base + 3 < nb) bsum[base + 3] = p;
}

__global__ __launch_bounds__(TPB) void scan3_kernel(int* bh,
                                                    const int* __restrict__ bsum,
                                                    int TOT) {
    int i = blockIdx.x * TPB + threadIdx.x;
    if (i < TOT) bh[i] += bsum[i >> 10];
}

// Phase 2: write payload. Each (bucket,chunk) segment has a SINGLE writer
// block -> lines combine in that XCD's L2 (no cross-block line sharing,
// which was R3's 64B-amplification failure mode).
__global__ __launch_bounds__(TPB) void binwrite_kernel(const int* __restrict__ dst,
                                                       const int* __restrict__ src,
                                                       const float* __restrict__ ew,
                                                       const int* __restrict__ bh,
                                                       u64* __restrict__ payload,
                                                       int E, int nbk, int nrb) {
    __shared__ int lcnt[MAXBK];
    __shared__ int gbase[MAXBK];
    const int t = threadIdx.x, blk = blockIdx.x;
    const int base = blk * CHUNK;
    const int cA = min(CHUNK, E - base);
    for (int i = t; i < nbk; i += TPB) {
        lcnt[i]  = 0;
        gbase[i] = bh[i * nrb + blk];
    }
    __syncthreads();
    for (int k = t; k < cA; k += TPB) {
        int e = base + k;
        int d = dst[e];
        int b = d >> 6;
        int pos = gbase[b] + atomicAdd(&lcnt[b], 1);
        u32 hi = ((u32)(d & (NB - 1)) << 17) | (u32)src[e];
        payload[pos] = ((u64)hi << 32) | (u64)__float_as_uint(ew[e]);
    }
}

// deg via LDS tile from binned payload -> dinv
__global__ __launch_bounds__(TPB) void deg_bin_kernel(const u64* __restrict__ payload,
                                                      const int* __restrict__ bh,
                                                      float* __restrict__ dinv,
                                                      int N, int E, int nbk, int nrb) {
    __shared__ float dt[NB];
    const int t = threadIdx.x, b = blockIdx.x;
    if (t < NB) dt[t] = 0.f;
    __syncthreads();
    const int bstart = bh[b * nrb];
    const int bend   = (b + 1 < nbk) ? bh[(b + 1) * nrb] : E;
    for (int i = bstart + t; i < bend; i += TPB) {
        u64 pl = payload[i];
        atomicAdd(&dt[(int)((pl >> 49) & (NB - 1))], __uint_as_float((u32)pl));
    }
    __syncthreads();
    if (t < NB) {
        int n = b * NB + t;
        if (n < N) dinv[n] = rsqrtf(dt[t] + 1.0f);
    }
}

// h1b[n,32] (bf16) = dinv[n] * (x[n,:] @ W[:,32]).  Block: 32 nodes.
__global__ __launch_bounds__(TPB) void gemm1_kernel(const float* __restrict__ x,
                                                    const float* __restrict__ W,
                                                    const float* __restrict__ dinv,
                                                    u16* __restrict__ h1b, int N) {
    __shared__ float Ws[128 * 32];
    __shared__ float xs[32 * 129];
    const int tid = threadIdx.x;
    const int nb  = blockIdx.x * 32;

    const float4* W4  = (const float4*)W;
    float4*       Ws4 = (float4*)Ws;
#pragma unroll
    for (int i = 0; i < 4; ++i) Ws4[tid + i * 256] = W4[tid + i * 256];

#pragma unroll
    for (int i = 0; i < 4; ++i) {
        int idx  = tid + i * 256;
        int node = idx >> 5;
        int col4 = idx & 31;
        if (nb + node < N) {
            float4 v = ((const float4*)(x + (size_t)nb * 128))[idx];
            float* p = &xs[node * 129 + col4 * 4];
            p[0] = v.x; p[1] = v.y; p[2] = v.z; p[3] = v.w;
        }
    }
    __syncthreads();

    const int nl = tid >> 3;
    const int og = (tid & 7) * 4;
    float a0 = 0.f, a1 = 0.f, a2 = 0.f, a3 = 0.f;
#pragma unroll 8
    for (int k = 0; k < 128; ++k) {
        float xv = xs[nl * 129 + k];
        const float* wp = &Ws[k * 32 + og];
        a0 = fmaf(xv, wp[0], a0);
        a1 = fmaf(xv, wp[1], a1);
        a2 = fmaf(xv, wp[2], a2);
        a3 = fmaf(xv, wp[3], a3);
    }
    int node = nb + nl;
    if (node < N) {
        float di = dinv[node];
        u16* o = &h1b[(size_t)node * 32 + og];
        o[0] = f32_to_bf16(a0 * di); o[1] = f32_to_bf16(a1 * di);
        o[2] = f32_to_bf16(a2 * di); o[3] = f32_to_bf16(a3 * di);
    }
}

// conv1 aggregate + relu + both projections fused. h1b is pre-scaled by
// dinv[s], so the edge chain is payload -> h1b only (4x unrolled).
//   tile[dl][f] += ew * h1b'[s][f]
//   hv = relu(di*(tile + h1b'[d]) + b1); g'[d] = di*(hv.wv); rpart[d] = hv.f2
__global__ __launch_bounds__(TPB) void agg1_kernel(const u64* __restrict__ payload,
                                                   const int* __restrict__ bh,
                                                   const float* __restrict__ dinv,
                                                   const u16* __restrict__ h1b,
                                                   const float* __restrict__ b1,
                                                   const float* __restrict__ W2,
                                                   const float* __restrict__ fc1_w,
                                                   const float* __restrict__ fc2_w,
                                                   float* __restrict__ gp,
                                                   float* __restrict__ rpart,
                                                   int N, int E, int nbk, int nrb) {
    __shared__ float tile[NB * 32];   // 8KB
    __shared__ float wv[32];
    __shared__ float f2[32];
    const int t = threadIdx.x, b = blockIdx.x;
    for (int i = t; i < NB * 32; i += TPB) tile[i] = 0.f;
    if (t < 32) {
        float a = 0.f;
#pragma unroll
        for (int j = 0; j < 16; ++j) a = fmaf(W2[t * 16 + j], fc1_w[j], a);
        wv[t] = a;
        f2[t] = fc2_w[t];
    }
    __syncthreads();

    const int bstart = bh[b * nrb];
    const int bend   = (b + 1 < nbk) ? bh[(b + 1) * nrb] : E;
    const int hw = t >> 5;            // half-wave 0..7
    const int f  = t & 31;

    int i = bstart + hw;
    for (; i + 24 < bend; i += 32) {  // 4 independent gathers in flight
        u64 pl0 = payload[i];
        u64 pl1 = payload[i + 8];
        u64 pl2 = payload[i + 16];
        u64 pl3 = payload[i + 24];
        u32 hi0 = (u32)(pl0 >> 32), hi1 = (u32)(pl1 >> 32);
        u32 hi2 = (u32)(pl2 >> 32), hi3 = (u32)(pl3 >> 32);
        float v0 = bf16_to_f32(h1b[(size_t)(hi0 & 0x1FFFF) * 32 + f]);
        float v1 = bf16_to_f32(h1b[(size_t)(hi1 & 0x1FFFF) * 32 + f]);
        float v2 = bf16_to_f32(h1b[(size_t)(hi2 & 0x1FFFF) * 32 + f]);
        float v3 = bf16_to_f32(h1b[(size_t)(hi3 & 0x1FFFF) * 32 + f]);
        atomicAdd(&tile[(int)((hi0 >> 17) & (NB - 1)) * 32 + f],
                  __uint_as_float((u32)pl0) * v0);
        atomicAdd(&tile[(int)((hi1 >> 17) & (NB - 1)) * 32 + f],
                  __uint_as_float((u32)pl1) * v1);
        atomicAdd(&tile[(int)((hi2 >> 17) & (NB - 1)) * 32 + f],
                  __uint_as_float((u32)pl2) * v2);
        atomicAdd(&tile[(int)((hi3 >> 17) & (NB - 1)) * 32 + f],
                  __uint_as_float((u32)pl3) * v3);
    }
    for (; i < bend; i += 8) {
        u64 pl = payload[i];
        u32 hi = (u32)(pl >> 32);
        float v = bf16_to_f32(h1b[(size_t)(hi & 0x1FFFF) * 32 + f]);
        atomicAdd(&tile[(int)((hi >> 17) & (NB - 1)) * 32 + f],
                  __uint_as_float((u32)pl) * v);
    }
    __syncthreads();

    // epilogue: 8 half-waves x 8 rows
    for (int r = hw; r < NB; r += 8) {
        int n = b * NB + r;
        if (n < N) {
            float di = dinv[n];
            float selfv = bf16_to_f32(h1b[(size_t)n * 32 + f]);
            float hv = di * (tile[r * 32 + f] + selfv) + b1[f];
            hv = fmaxf(hv, 0.f);
            float a = hv * wv[f];
            float c = hv * f2[f];
#pragma unroll
            for (int m = 1; m < 32; m <<= 1) {
                a += __shfl_xor(a, m);
                c += __shfl_xor(c, m);
            }
            if (f == 0) { gp[n] = di * a; rpart[n] = c; }
        }
    }
}

// conv2 (scalar) + fc heads. gp is pre-scaled by dinv[s].
//   st[dl] += ew*gp[s];  x1f = di*(st + gp[d]) + cst;  c = sigmoid(x1f);
//   r = rpart + c*fc2_w[32] + fc2_b
__global__ __launch_bounds__(TPB) void agg2_kernel(const u64* __restrict__ payload,
                                                   const int* __restrict__ bh,
                                                   const float* __restrict__ dinv,
                                                   const float* __restrict__ gp,
                                                   const float* __restrict__ rpart,
                                                   const float* __restrict__ b2,
                                                   const float* __restrict__ fc1_w,
                                                   const float* __restrict__ fc1_b,
                                                   const float* __restrict__ fc2_w,
                                                   const float* __restrict__ fc2_b,
                                                   float* __restrict__ out,
                                                   int N, int E, int nbk, int nrb) {
    __shared__ float st[NB];
    const int t = threadIdx.x, b = blockIdx.x;
    if (t < NB) st[t] = 0.f;
    __syncthreads();
    const int bstart = bh[b * nrb];
    const int bend   = (b + 1 < nbk) ? bh[(b + 1) * nrb] : E;
    for (int i = bstart + t; i < bend; i += TPB) {
        u64 pl = payload[i];
        u32 hi = (u32)(pl >> 32);
        float val = __uint_as_float((u32)pl) * gp[hi & 0x1FFFF];
        atomicAdd(&st[(int)((hi >> 17) & (NB - 1))], val);
    }
    __syncthreads();
    if (t < NB) {
        int n = b * NB + t;
        if (n < N) {
            float cst = fc1_b[0];
#pragma unroll
            for (int j = 0; j < 16; ++j) cst = fmaf(b2[j], fc1_w[j], cst);
            float di  = dinv[n];
            float x1f = di * (st[t] + gp[n]) + cst;
            float c   = 1.0f / (1.0f + expf(-x1f));
            out[n]     = rpart[n] + c * fc2_w[32] + fc2_b[0];
            out[N + n] = x1f;
        }
    }
}

extern "C" void kernel_launch(void* const* d_in, const int* in_sizes, int n_in,
                              void* d_out, int out_size, void* d_ws, size_t ws_size,
                              hipStream_t stream) {
    const float* x     = (const float*)d_in[0];
    const int*   ei    = (const int*)d_in[1];
    const float* ew    = (const float*)d_in[2];
    const float* W1    = (const float*)d_in[3];
    const float* b1    = (const float*)d_in[4];
    const float* W2    = (const float*)d_in[5];
    const float* b2    = (const float*)d_in[6];
    const float* fc1_w = (const float*)d_in[7];
    const float* fc1_b = (const float*)d_in[8];
    const float* fc2_w = (const float*)d_in[9];
    const float* fc2_b = (const float*)d_in[10];

    const int N = in_sizes[0] / 128;
    const int E = in_sizes[2];
    const int* src = ei;
    const int* dst = ei + E;

    const int nbk = (N + NB - 1) / NB;            // 1563 (needs N < 2^17)
    const int nrb = (E + CHUNK - 1) / CHUNK;      // 391
    const int TOT = nbk * nrb;                    // ~611K

    // ws (4B units): payload 2E | h1b 16N | dinv N | gp N | rpart N |
    //                bh TOT | bsum 1024       total ~35.7 MB (< 38.8 proven)
    u64*   payload = (u64*)d_ws;
    u16*   h1b     = (u16*)((float*)d_ws + (size_t)2 * E);
    float* dinv    = (float*)d_ws + (size_t)2 * E + (size_t)16 * N;
    float* gp      = dinv + N;
    float* rpart   = gp + N;
    int*   bh      = (int*)(rpart + N);
    int*   bsum    = bh + TOT;

    binhist_kernel<<<nrb, TPB, 0, stream>>>(dst, bh, E, nbk, nrb);
    const int nb1 = (TOT + 1023) / 1024;          // ~597 <= 1024
    scan1_kernel<<<nb1, TPB, 0, stream>>>(bh, bsum, TOT);
    scan2_kernel<<<1, TPB, 0, stream>>>(bsum, nb1);
    scan3_kernel<<<(TOT + TPB - 1) / TPB, TPB, 0, stream>>>(bh, bsum, TOT);
    binwrite_kernel<<<nrb, TPB, 0, stream>>>(dst, src, ew, bh, payload, E, nbk, nrb);

    deg_bin_kernel<<<nbk, TPB, 0, stream>>>(payload, bh, dinv, N, E, nbk, nrb);
    gemm1_kernel<<<(N + 31) / 32, TPB, 0, stream>>>(x, W1, dinv, h1b, N);
    agg1_kernel<<<nbk, TPB, 0, stream>>>(payload, bh, dinv, h1b, b1, W2, fc1_w,
                                         fc2_w, gp, rpart, N, E, nbk, nrb);
    agg2_kernel<<<nbk, TPB, 0, stream>>>(payload, bh, dinv, gp, rpart, b2, fc1_w,
                                         fc1_b, fc2_w, fc2_b, (float*)d_out,
                                         N, E, nbk, nrb);
}